// Round 21
// baseline (2714.000 us; speedup 1.0000x reference)
//
#include <hip/hip_runtime.h>
#include <hip/hip_bf16.h>
#include <math.h>

typedef __bf16 bf16_t;
typedef __attribute__((ext_vector_type(8))) __bf16 bf16x8;
typedef __attribute__((ext_vector_type(4))) __bf16 bf16x4;
typedef __attribute__((ext_vector_type(4))) float f32x4;

static constexpr int B_ = 16, C_ = 16, T_ = 128, H_ = 8, L_ = 12;
static constexpr int NSEQ = C_ * T_ + 1;      // 2049
static constexpr int M_ = B_ * NSEQ;          // 32784
static constexpr int MPAD = 32896;            // 257*128
static constexpr float EPS_ = 1e-5f;

__device__ __forceinline__ float wave_sum(float s) {
    #pragma unroll
    for (int o = 1; o < 64; o <<= 1) s += __shfl_xor(s, o);
    return s;
}

// fast erf-based GELU (A&S 7.1.26, |eps|<1.5e-7)
__device__ __forceinline__ float gelu_f(float v) {
    float ax = fabsf(v) * 0.70710678118654752f;
    float t = 1.f / (1.f + 0.3275911f * ax);
    float p = t * (0.254829592f + t * (-0.284496736f + t * (1.421413741f +
              t * (-1.453152027f + t * 1.061405429f))));
    float erf_abs = 1.f - p * __expf(-ax * ax);
    float erf = (v < 0.f) ? -erf_abs : erf_abs;
    return 0.5f * v * (1.f + erf);
}

// ---------------- weight conversion to W' layout [L][K/8][N][8] ----------------
__global__ void conv_w(const float* __restrict__ W, bf16_t* __restrict__ out, int K, int N) {
    size_t i = (size_t)blockIdx.x * 256 + threadIdx.x;
    size_t per = (size_t)K * N;
    size_t tot = (size_t)L_ * per;
    if (i >= tot) return;
    int kl = i & 7;
    size_t r = i >> 3;
    int n = r % N;
    size_t r2 = r / N;
    int kh = r2 % (K >> 3);
    int l = r2 / (K >> 3);
    out[i] = (bf16_t)W[(size_t)l * per + (size_t)(kh * 8 + kl) * N + n];
}

__global__ void conv_wq3(const float* __restrict__ Wq, const float* __restrict__ Wk,
                         const float* __restrict__ Wv, bf16_t* __restrict__ out) {
    size_t i = (size_t)blockIdx.x * 256 + threadIdx.x;
    size_t tot = (size_t)L_ * 32 * 768 * 8;
    if (i >= tot) return;
    int kl = i & 7;
    size_t r = i >> 3;
    int n = r % 768;
    size_t r2 = r / 768;
    int kh = r2 % 32;
    int l = r2 / 32;
    const float* src = (n < 256) ? Wq : (n < 512) ? Wk : Wv;
    out[i] = (bf16_t)src[(size_t)l * 65536 + (size_t)(kh * 8 + kl) * 256 + (n & 255)];
}

// ---------------- embedding ----------------
__global__ void embed_kernel(const int* __restrict__ x, const float* __restrict__ emb,
                             const float* __restrict__ ch, const float* __restrict__ cls,
                             float* __restrict__ h) {
    int wave = threadIdx.x >> 6, lane = threadIdx.x & 63;
    int row = blockIdx.x * 4 + wave;
    int d0 = lane * 4;
    float4 o;
    int b = row / NSEQ, n = row % NSEQ;
    if (n == 0) {
        o = *(const float4*)(cls + d0);
    } else {
        int idx = n - 1;
        int c = idx / T_, t = idx % T_;
        int tok = x[(b * C_ + c) * T_ + t];
        float4 ev = *(const float4*)(emb + (size_t)tok * 256 + d0);
        float4 cv = *(const float4*)(ch + c * 256 + d0);
        const float kdiv = -0.03597789207803197f;   // -ln(10000)/256
        float f0 = __expf(d0 * kdiv);
        float f2 = __expf((d0 + 2) * kdiv);
        float a0 = t * f0, a2 = t * f2;
        o.x = ev.x + cv.x + sinf(a0);
        o.y = ev.y + cv.y + cosf(a0);
        o.z = ev.z + cv.z + sinf(a2);
        o.w = ev.w + cv.w + cosf(a2);
    }
    *(float4*)(h + (size_t)row * 256 + d0) = o;
}

// ============================================================================
// 128-row A-resident barrier-free GEMM (swapped-operand MFMA, coalesced epi).
// T5 setprio around the per-tile MFMA cluster.
// SRC 0: A = layer_norm(h fp32).  EPI 0: Cb = bf16(acc).  EPI 1: Cf += acc+bias.
// ============================================================================
template <int SRC, int EPI, int NT>
__launch_bounds__(512)
__global__ void gemm_ar(const void* __restrict__ Asrc, const float* __restrict__ lng,
                        const float* __restrict__ lnb, const bf16_t* __restrict__ Wp,
                        const float* __restrict__ bias, float* __restrict__ Cf,
                        bf16_t* __restrict__ Cb, int N) {
    __shared__ bf16_t yn[128 * 256];
    int tid = threadIdx.x;
    int row0 = blockIdx.y * 128;
    int row = tid >> 2, q4 = tid & 3;
    int sx = row & 7;

    if (SRC == 0) {
        const float* rp = (const float*)Asrc + (size_t)(row0 + row) * 256;
        bool ok = (row0 + row) < M_;
        float v[64];
        float sum = 0.f, sq = 0.f;
        #pragma unroll
        for (int j = 0; j < 16; ++j) {
            float4 t = ok ? *(const float4*)(rp + (q4 + j * 4) * 4)
                          : float4{0.f, 0.f, 0.f, 0.f};
            v[j*4+0] = t.x; v[j*4+1] = t.y; v[j*4+2] = t.z; v[j*4+3] = t.w;
            sum += t.x + t.y + t.z + t.w;
            sq  += t.x*t.x + t.y*t.y + t.z*t.z + t.w*t.w;
        }
        sum += __shfl_xor(sum, 1); sum += __shfl_xor(sum, 2);
        sq  += __shfl_xor(sq, 1);  sq  += __shfl_xor(sq, 2);
        float mean = sum * (1.f/256.f);
        float var  = sq * (1.f/256.f) - mean*mean;
        float rs = rsqrtf(var + EPS_);
        #pragma unroll
        for (int j = 0; j < 16; ++j) {
            int ce = q4 + j * 4;
            int colb = ce * 4;
            float4 gv = *(const float4*)(lng + colb);
            float4 bv = *(const float4*)(lnb + colb);
            bf16x4 o4;
            o4[0] = (bf16_t)((v[j*4+0]-mean)*rs*gv.x + bv.x);
            o4[1] = (bf16_t)((v[j*4+1]-mean)*rs*gv.y + bv.y);
            o4[2] = (bf16_t)((v[j*4+2]-mean)*rs*gv.z + bv.z);
            o4[3] = (bf16_t)((v[j*4+3]-mean)*rs*gv.w + bv.w);
            int cg = ce >> 1, hf = ce & 1;
            *(bf16x4*)(&yn[row*256 + ((cg ^ sx) << 3) + hf*4]) = o4;
        }
    } else {
        const bf16_t* rp = (const bf16_t*)Asrc + (size_t)(row0 + row) * 256;
        #pragma unroll
        for (int j = 0; j < 8; ++j) {
            int cg = q4 * 8 + j;
            bf16x8 t = *(const bf16x8*)(rp + cg * 8);
            *(bf16x8*)(&yn[row*256 + ((cg ^ sx) << 3)]) = t;
        }
    }
    __syncthreads();

    int lane = tid & 63, wave = tid >> 6;
    int l15 = lane & 15, ksel = lane >> 4;
    #pragma unroll
    for (int t = 0; t < NT; ++t) {
        int tbase = (blockIdx.x * NT + t) * 128 + wave * 16;
        int col = tbase + l15;
        const bf16_t* bp = Wp + ((size_t)ksel * N + col) * 8;
        f32x4 acc[8] = {};
        __builtin_amdgcn_s_setprio(1);
        #pragma unroll
        for (int kk = 0; kk < 8; ++kk) {
            bf16x8 bf = *(const bf16x8*)(bp + (size_t)kk * 32 * N);
            #pragma unroll
            for (int m = 0; m < 8; ++m) {
                int r = m * 16 + l15;
                bf16x8 af = *(const bf16x8*)(&yn[r*256 + (((kk*4+ksel) ^ (r&7)) << 3)]);
                acc[m] = __builtin_amdgcn_mfma_f32_16x16x32_bf16(bf, af, acc[m], 0, 0, 0);
            }
        }
        __builtin_amdgcn_s_setprio(0);
        int colb = tbase + ksel * 4;
        #pragma unroll
        for (int m = 0; m < 8; ++m) {
            int r = row0 + m * 16 + l15;
            if (r < M_) {
                if (EPI == 0) {
                    bf16x4 o4;
                    #pragma unroll
                    for (int i = 0; i < 4; ++i) o4[i] = (bf16_t)acc[m][i];
                    *(bf16x4*)(Cb + (size_t)r * N + colb) = o4;
                } else {
                    float4 bv = *(const float4*)(bias + colb);
                    float4* hp = (float4*)(Cf + (size_t)r * 256 + colb);
                    float4 hv = *hp;
                    hv.x += acc[m][0] + bv.x; hv.y += acc[m][1] + bv.y;
                    hv.z += acc[m][2] + bv.z; hv.w += acc[m][3] + bv.w;
                    *hp = hv;
                }
            }
        }
    }
}

// ---------------- ctx partial: sum_n exp(k)*v ; colsum ----------------
__global__ void ctx_kernel(const bf16_t* __restrict__ qkv,
                           float* __restrict__ ctx_part, float* __restrict__ colsum_part) {
    int blk = blockIdx.x;                // bh*8 + s
    int bh = blk >> 3, s = blk & 7;
    int b = bh >> 3, hh = bh & 7;
    int n0 = s * 257, n1 = min(n0 + 257, NSEQ);
    int d = threadIdx.x & 31, eg = threadIdx.x >> 5;
    float acc[4] = {0.f, 0.f, 0.f, 0.f};
    float ksum = 0.f;
    __shared__ float ks[64][32];
    __shared__ float vs[64][32];
    const bf16_t* kbase = qkv + (size_t)b * NSEQ * 768 + 256 + hh * 32;
    const bf16_t* vbase = kbase + 256;
    int lr = threadIdx.x >> 2, lc = (threadIdx.x & 3) * 8;
    for (int c0 = n0; c0 < n1; c0 += 64) {
        int rows = min(64, n1 - c0);
        if (lr < rows) {
            bf16x8 kv8 = *(const bf16x8*)(kbase + (size_t)(c0 + lr) * 768 + lc);
            bf16x8 vv8 = *(const bf16x8*)(vbase + (size_t)(c0 + lr) * 768 + lc);
            #pragma unroll
            for (int j = 0; j < 8; ++j) {
                ks[lr][lc + j] = (float)kv8[j];
                vs[lr][lc + j] = (float)vv8[j];
            }
        }
        __syncthreads();
        for (int r = 0; r < rows; ++r) {
            float ek = __expf(ks[r][d]);
            if (eg == 0) ksum += ek;
            const float* vr = &vs[r][eg * 4];
            acc[0] += ek * vr[0]; acc[1] += ek * vr[1];
            acc[2] += ek * vr[2]; acc[3] += ek * vr[3];
        }
        __syncthreads();
    }
    float* cp = ctx_part + ((size_t)blk * 32 + d) * 32 + eg * 4;
    cp[0] = acc[0]; cp[1] = acc[1]; cp[2] = acc[2]; cp[3] = acc[3];
    if (eg == 0) colsum_part[blk * 32 + d] = ksum;
}

// ============================================================================
// CW assembly: CW_b[h*32+d][c] = (sum_s ctxp)/csum  @  Wo_h  -> W' bf16 layout.
// ============================================================================
__global__ void cw_kernel(const float* __restrict__ ctxp, const float* __restrict__ csump,
                          const float* __restrict__ Wo, bf16_t* __restrict__ cwp) {
    int bh = blockIdx.x, b = bh >> 3, hh = bh & 7;
    __shared__ float ctxn[1024];    // [d][e]
    __shared__ float cs[32];
    __shared__ float wos[32][257];  // [e][c], padded
    int t = threadIdx.x;
    for (int i = t; i < 1024; i += 256) {
        float s = 0.f;
        #pragma unroll
        for (int ss = 0; ss < 8; ++ss) s += ctxp[(size_t)(bh * 8 + ss) * 1024 + i];
        ctxn[i] = s;
    }
    if (t < 32) {
        float s = 0.f;
        #pragma unroll
        for (int ss = 0; ss < 8; ++ss) s += csump[(bh * 8 + ss) * 32 + t];
        cs[t] = s;
    }
    for (int i = t; i < 8192; i += 256) {
        int e = i >> 8, c = i & 255;
        wos[e][c] = Wo[(size_t)(hh * 32 + e) * 256 + c];
    }
    __syncthreads();
    float out[32] = {};
    #pragma unroll 4
    for (int e = 0; e < 32; ++e) {
        float w = wos[e][t];
        #pragma unroll
        for (int d = 0; d < 32; ++d) out[d] += ctxn[d * 32 + e] * w;
    }
    #pragma unroll
    for (int d = 0; d < 32; ++d) {
        int kh = hh * 4 + (d >> 3);
        cwp[((size_t)(b * 32 + kh) * 256 + t) * 8 + (d & 7)] = (bf16_t)(out[d] / cs[d]);
    }
}

// ============================================================================
// P@CW gemm: h += softmax32(q)*scale @ CW_b + bo.
// 64-row stripes, grid (1, 33, 16) = 528 blocks (~2/CU, balanced).
// ============================================================================
__launch_bounds__(512)
__global__ void gemm_pv(const bf16_t* __restrict__ qkv, const bf16_t* __restrict__ cwp,
                        const float* __restrict__ bo, float* __restrict__ h) {
    __shared__ bf16_t yn[64 * 256];   // 32 KB
    int tid = threadIdx.x;
    int b = blockIdx.z;
    int row0l = blockIdx.y * 64;
    int row = tid >> 3, t8 = tid & 7;   // 8 threads/row, each owns one 32-elem head group
    int sx = row & 7;
    {
        int rl = row0l + row;
        bool ok = rl < NSEQ;
        const bf16_t* qp = qkv + ((size_t)b * NSEQ + (ok ? rl : 0)) * 768 + t8 * 32;
        float v[32];
        float mx = -1e30f;
        #pragma unroll
        for (int jj = 0; jj < 4; ++jj) {
            bf16x8 t8v = *(const bf16x8*)(qp + jj * 8);
            #pragma unroll
            for (int e = 0; e < 8; ++e) {
                float f = (float)t8v[e];
                v[jj * 8 + e] = f;
                mx = fmaxf(mx, f);
            }
        }
        float s = 0.f;
        #pragma unroll
        for (int e2 = 0; e2 < 32; ++e2) { v[e2] = __expf(v[e2] - mx); s += v[e2]; }
        float p = ok ? (0.17677669529663689f / s) : 0.f;
        #pragma unroll
        for (int j = 0; j < 4; ++j) {
            int c = t8 * 4 + j;
            bf16x8 o8;
            #pragma unroll
            for (int e3 = 0; e3 < 8; ++e3) o8[e3] = (bf16_t)(v[j * 8 + e3] * p);
            *(bf16x8*)(&yn[row * 256 + ((c ^ sx) << 3)]) = o8;
        }
    }
    __syncthreads();

    int lane = tid & 63, wave = tid >> 6;
    int l15 = lane & 15, ksel = lane >> 4;
    int sxr = l15 & 7;
    const bf16_t* CWb = cwp + (size_t)b * 32 * 256 * 8;
    #pragma unroll
    for (int t = 0; t < 2; ++t) {
        int tbase = t * 128 + wave * 16;
        int col = tbase + l15;
        const bf16_t* bp = CWb + ((size_t)ksel * 256 + col) * 8;
        f32x4 acc[4] = {};
        __builtin_amdgcn_s_setprio(1);
        #pragma unroll
        for (int kk = 0; kk < 8; ++kk) {
            bf16x8 bf = *(const bf16x8*)(bp + (size_t)kk * 32 * 256);
            #pragma unroll
            for (int m = 0; m < 4; ++m) {
                int r = m * 16 + l15;
                bf16x8 af = *(const bf16x8*)(&yn[r*256 + (((kk*4+ksel) ^ sxr) << 3)]);
                acc[m] = __builtin_amdgcn_mfma_f32_16x16x32_bf16(bf, af, acc[m], 0, 0, 0);
            }
        }
        __builtin_amdgcn_s_setprio(0);
        int colb = tbase + ksel * 4;
        float4 bv = *(const float4*)(bo + colb);
        #pragma unroll
        for (int m = 0; m < 4; ++m) {
            int rl = row0l + m * 16 + l15;
            if (rl < NSEQ) {
                float4* hp = (float4*)(h + ((size_t)b * NSEQ + rl) * 256 + colb);
                float4 hv = *hp;
                hv.x += acc[m][0] + bv.x; hv.y += acc[m][1] + bv.y;
                hv.z += acc[m][2] + bv.z; hv.w += acc[m][3] + bv.w;
                *hp = hv;
            }
        }
    }
}

// ============================================================================
// Fused LN2 + FF1 + GELU + FF2 + residual.  32-row stripe, 4 waves, 24KB LDS
// -> 4+ blocks/CU co-resident (cross-block TLP hides the per-chunk chain).
// 16 chunks of 64 ff-cols; T5 setprio; T14 early W2 loads (8 frags).
// ============================================================================
__launch_bounds__(256)
__global__ void fused_ff(const float* __restrict__ hsrc, const float* __restrict__ lng,
                         const float* __restrict__ lnb, const bf16_t* __restrict__ W1p,
                         const float* __restrict__ b1v, const bf16_t* __restrict__ W2p,
                         const float* __restrict__ b2v, float* __restrict__ hio) {
    __shared__ bf16_t yn[32 * 256];   // 16 KB
    __shared__ bf16_t ps[32 * 64];    // 4 KB
    int tid = threadIdx.x;
    int row0 = blockIdx.x * 32;
    int row = tid >> 3, t8 = tid & 7;
    int sx = row & 7;
    {
        const float* rp = hsrc + (size_t)(row0 + row) * 256 + t8 * 32;
        bool ok = (row0 + row) < M_;
        float sum = 0.f, sq = 0.f;
        #pragma unroll
        for (int j = 0; j < 8; ++j) {
            float4 t = ok ? *(const float4*)(rp + j * 4) : float4{0.f, 0.f, 0.f, 0.f};
            sum += t.x + t.y + t.z + t.w;
            sq  += t.x * t.x + t.y * t.y + t.z * t.z + t.w * t.w;
        }
        sum += __shfl_xor(sum, 1); sum += __shfl_xor(sum, 2); sum += __shfl_xor(sum, 4);
        sq  += __shfl_xor(sq, 1);  sq  += __shfl_xor(sq, 2);  sq  += __shfl_xor(sq, 4);
        float mean = sum * (1.f / 256.f);
        float rs = rsqrtf(sq * (1.f / 256.f) - mean * mean + EPS_);
        #pragma unroll
        for (int j = 0; j < 4; ++j) {
            int c = t8 * 4 + j;
            int colb = c * 8;
            float4 a = ok ? *(const float4*)(rp + j * 8)     : float4{0.f, 0.f, 0.f, 0.f};
            float4 b = ok ? *(const float4*)(rp + j * 8 + 4) : float4{0.f, 0.f, 0.f, 0.f};
            float4 g0 = *(const float4*)(lng + colb);
            float4 g1 = *(const float4*)(lng + colb + 4);
            float4 h0 = *(const float4*)(lnb + colb);
            float4 h1 = *(const float4*)(lnb + colb + 4);
            bf16x8 o8;
            o8[0] = (bf16_t)((a.x - mean) * rs * g0.x + h0.x);
            o8[1] = (bf16_t)((a.y - mean) * rs * g0.y + h0.y);
            o8[2] = (bf16_t)((a.z - mean) * rs * g0.z + h0.z);
            o8[3] = (bf16_t)((a.w - mean) * rs * g0.w + h0.w);
            o8[4] = (bf16_t)((b.x - mean) * rs * g1.x + h1.x);
            o8[5] = (bf16_t)((b.y - mean) * rs * g1.y + h1.y);
            o8[6] = (bf16_t)((b.z - mean) * rs * g1.z + h1.z);
            o8[7] = (bf16_t)((b.w - mean) * rs * g1.w + h1.w);
            *(bf16x8*)(&yn[row * 256 + ((c ^ sx) << 3)]) = o8;
        }
    }
    __syncthreads();

    int lane = tid & 63, wave = tid >> 6;      // 4 waves
    int l15 = lane & 15, ksel = lane >> 4;
    int sxr = l15 & 7;
    f32x4 oacc[2][4] = {};

    for (int kc = 0; kc < 16; ++kc) {
        // ---- T14: issue W2 loads for this chunk EARLY (kh = kc*8 + kk*4 + ksel) ----
        bf16x8 w2[2][4];
        {
            #pragma unroll
            for (int kk = 0; kk < 2; ++kk) {
                const bf16_t* b2base = W2p + (size_t)(kc * 8 + kk * 4 + ksel) * 256 * 8;
                #pragma unroll
                for (int c = 0; c < 4; ++c)
                    w2[kk][c] = *(const bf16x8*)(b2base + (size_t)(wave * 64 + c * 16 + l15) * 8);
            }
        }
        // ---- FF1: pacc = yn @ W1[:, chunk]  (64-col chunk) ----
        int fcol = kc * 64 + wave * 16 + l15;
        const bf16_t* bp = W1p + ((size_t)ksel * 1024 + fcol) * 8;
        f32x4 pacc[2] = {};
        __builtin_amdgcn_s_setprio(1);
        #pragma unroll
        for (int kk = 0; kk < 8; ++kk) {
            bf16x8 bf = *(const bf16x8*)(bp + (size_t)kk * 32 * 1024);
            #pragma unroll
            for (int m = 0; m < 2; ++m) {
                int r = m * 16 + l15;
                bf16x8 af = *(const bf16x8*)(&yn[r * 256 + (((kk * 4 + ksel) ^ sxr) << 3)]);
                pacc[m] = __builtin_amdgcn_mfma_f32_16x16x32_bf16(bf, af, pacc[m], 0, 0, 0);
            }
        }
        __builtin_amdgcn_s_setprio(0);
        float4 b1a = *(const float4*)(b1v + kc * 64 + wave * 16 + ksel * 4);
        __syncthreads();   // previous chunk's FF2 reads of ps are done
        // ---- gelu -> ps ----
        int pcl = wave * 16 + ksel * 4;
        int pc = pcl >> 3, pofs = pcl & 7;
        #pragma unroll
        for (int m = 0; m < 2; ++m) {
            bf16x4 o4;
            o4[0] = (bf16_t)gelu_f(pacc[m][0] + b1a.x);
            o4[1] = (bf16_t)gelu_f(pacc[m][1] + b1a.y);
            o4[2] = (bf16_t)gelu_f(pacc[m][2] + b1a.z);
            o4[3] = (bf16_t)gelu_f(pacc[m][3] + b1a.w);
            *(bf16x4*)(&ps[(m * 16 + l15) * 64 + ((pc ^ sxr) << 3) + pofs]) = o4;
        }
        __syncthreads();
        // ---- FF2 partial: oacc += ps @ W2[chunk, :]  (weights preloaded) ----
        __builtin_amdgcn_s_setprio(1);
        #pragma unroll
        for (int kk = 0; kk < 2; ++kk) {
            #pragma unroll
            for (int m = 0; m < 2; ++m) {
                int r = m * 16 + l15;
                bf16x8 af = *(const bf16x8*)(&ps[r * 64 + (((kk * 4 + ksel) ^ sxr) << 3)]);
                #pragma unroll
                for (int c = 0; c < 4; ++c)
                    oacc[m][c] = __builtin_amdgcn_mfma_f32_16x16x32_bf16(w2[kk][c], af, oacc[m][c], 0, 0, 0);
            }
        }
        __builtin_amdgcn_s_setprio(0);
    }

    #pragma unroll
    for (int c = 0; c < 4; ++c) {
        int colb = wave * 64 + c * 16 + ksel * 4;
        float4 bv = *(const float4*)(b2v + colb);
        #pragma unroll
        for (int m = 0; m < 2; ++m) {
            int r = row0 + m * 16 + l15;
            if (r < M_) {
                float4* hp = (float4*)(hio + (size_t)r * 256 + colb);
                float4 hv = *hp;
                hv.x += oacc[m][c][0] + bv.x; hv.y += oacc[m][c][1] + bv.y;
                hv.z += oacc[m][c][2] + bv.z; hv.w += oacc[m][c][3] + bv.w;
                *hp = hv;
            }
        }
    }
}

// ---------------- classifier head: one wave per (b, cls) ----------------
__global__ void head_kernel(const float* __restrict__ h, const float* __restrict__ Wh,
                            const float* __restrict__ bh, float* __restrict__ out) {
    int idx = blockIdx.x;                 // 0..79 = b*5 + c
    int b = idx / 5, c = idx % 5;
    int lane = threadIdx.x;
    const float* xp = h + (size_t)b * NSEQ * 256;
    float s = 0.f;
    #pragma unroll
    for (int d0 = 0; d0 < 256; d0 += 64) s += xp[d0 + lane] * Wh[(d0 + lane) * 5 + c];
    s = wave_sum(s);
    if (lane == 0) out[idx] = s + bh[c];
}

extern "C" void kernel_launch(void* const* d_in, const int* in_sizes, int n_in,
                              void* d_out, int out_size, void* d_ws, size_t ws_size,
                              hipStream_t stream) {
    const int*   x    = (const int*)d_in[0];
    const float* emb  = (const float*)d_in[1];
    const float* ch   = (const float*)d_in[2];
    const float* cls  = (const float*)d_in[3];
    const float* Wq   = (const float*)d_in[4];
    const float* Wk   = (const float*)d_in[5];
    const float* Wv   = (const float*)d_in[6];
    const float* Wo   = (const float*)d_in[7];
    const float* bo   = (const float*)d_in[8];
    const float* g1   = (const float*)d_in[9];
    const float* b1   = (const float*)d_in[10];
    const float* W1   = (const float*)d_in[11];
    const float* bf1  = (const float*)d_in[12];
    const float* W2   = (const float*)d_in[13];
    const float* bf2  = (const float*)d_in[14];
    const float* g2   = (const float*)d_in[15];
    const float* b2   = (const float*)d_in[16];
    const float* Wh   = (const float*)d_in[17];
    const float* bh   = (const float*)d_in[18];

    char* ws = (char*)d_ws;
    size_t off = 0;
    float*  h      = (float*)(ws + off);  off += (size_t)M_ * 256 * 4;            // 33,570,816
    bf16_t* qkv    = (bf16_t*)(ws + off); off += (size_t)MPAD * 768 * 2;          // 50,528,256
    float*  ctxp   = (float*)(ws + off);  off += (size_t)16 * 8 * 8 * 1024 * 4;   // 4,194,304
    float*  csump  = (float*)(ws + off);  off += (size_t)16 * 8 * 8 * 32 * 4;     // 131,072
    bf16_t* cwp    = (bf16_t*)(ws + off); off += (size_t)16 * 32 * 256 * 8 * 2;   // 2,097,152
    bf16_t* wqkv_p = (bf16_t*)(ws + off); off += (size_t)L_ * 768 * 256 * 2;      // 4,718,592
    bf16_t* w1_p   = (bf16_t*)(ws + off); off += (size_t)L_ * 1024 * 256 * 2;     // 6,291,456
    bf16_t* w2_p   = (bf16_t*)(ws + off); off += (size_t)L_ * 256 * 1024 * 2;     // 6,291,456
    (void)ws_size; (void)in_sizes; (void)n_in; (void)out_size;

    conv_wq3<<<9216, 256, 0, stream>>>(Wq, Wk, Wv, wqkv_p);
    conv_w<<<12288, 256, 0, stream>>>(W1, w1_p, 256, 1024);
    conv_w<<<12288, 256, 0, stream>>>(W2, w2_p, 1024, 256);

    embed_kernel<<<M_ / 4, 256, 0, stream>>>(x, emb, ch, cls, h);

    for (int l = 0; l < L_; ++l) {
        // LN1 + QKV -> qkv bf16 [M][768]
        gemm_ar<0, 0, 3><<<dim3(2, 257), 512, 0, stream>>>(
            h, g1 + l * 256, b1 + l * 256, wqkv_p + (size_t)l * 768 * 256,
            nullptr, nullptr, qkv, 768);
        ctx_kernel<<<1024, 256, 0, stream>>>(qkv, ctxp, csump);
        // CW_b = normalize(ctx) @ Wo_h  -> W' bf16
        cw_kernel<<<128, 256, 0, stream>>>(ctxp, csump, Wo + (size_t)l * 65536, cwp);
        // h += softmax(q)*scale @ CW_b + bo
        gemm_pv<<<dim3(1, 33, 16), 512, 0, stream>>>(qkv, cwp, bo + l * 256, h);
        // LN2 + FF1 + GELU + FF2 + residual (fused, 32-row blocks)
        fused_ff<<<1025, 256, 0, stream>>>(
            h, g2 + l * 256, b2 + l * 256, w1_p + (size_t)l * 1024 * 256,
            bf1 + l * 1024, w2_p + (size_t)l * 256 * 1024, bf2 + l * 256, h);
    }

    head_kernel<<<80, 64, 0, stream>>>(h, Wh, bh, (float*)d_out);
}

// Round 22
// 2676.024 us; speedup vs baseline: 1.0142x; 1.0142x over previous
//
#include <hip/hip_runtime.h>
#include <hip/hip_bf16.h>
#include <math.h>

typedef __bf16 bf16_t;
typedef __attribute__((ext_vector_type(8))) __bf16 bf16x8;
typedef __attribute__((ext_vector_type(4))) __bf16 bf16x4;
typedef __attribute__((ext_vector_type(4))) float f32x4;

static constexpr int B_ = 16, C_ = 16, T_ = 128, H_ = 8, L_ = 12;
static constexpr int NSEQ = C_ * T_ + 1;      // 2049
static constexpr int M_ = B_ * NSEQ;          // 32784
static constexpr int MPAD = 32896;            // 257*128
static constexpr float EPS_ = 1e-5f;

__device__ __forceinline__ float wave_sum(float s) {
    #pragma unroll
    for (int o = 1; o < 64; o <<= 1) s += __shfl_xor(s, o);
    return s;
}

// fast erf-based GELU (A&S 7.1.26, |eps|<1.5e-7)
__device__ __forceinline__ float gelu_f(float v) {
    float ax = fabsf(v) * 0.70710678118654752f;
    float t = 1.f / (1.f + 0.3275911f * ax);
    float p = t * (0.254829592f + t * (-0.284496736f + t * (1.421413741f +
              t * (-1.453152027f + t * 1.061405429f))));
    float erf_abs = 1.f - p * __expf(-ax * ax);
    float erf = (v < 0.f) ? -erf_abs : erf_abs;
    return 0.5f * v * (1.f + erf);
}

// ---------------- weight conversion to W' layout [L][K/8][N][8] ----------------
__global__ void conv_w(const float* __restrict__ W, bf16_t* __restrict__ out, int K, int N) {
    size_t i = (size_t)blockIdx.x * 256 + threadIdx.x;
    size_t per = (size_t)K * N;
    size_t tot = (size_t)L_ * per;
    if (i >= tot) return;
    int kl = i & 7;
    size_t r = i >> 3;
    int n = r % N;
    size_t r2 = r / N;
    int kh = r2 % (K >> 3);
    int l = r2 / (K >> 3);
    out[i] = (bf16_t)W[(size_t)l * per + (size_t)(kh * 8 + kl) * N + n];
}

__global__ void conv_wq3(const float* __restrict__ Wq, const float* __restrict__ Wk,
                         const float* __restrict__ Wv, bf16_t* __restrict__ out) {
    size_t i = (size_t)blockIdx.x * 256 + threadIdx.x;
    size_t tot = (size_t)L_ * 32 * 768 * 8;
    if (i >= tot) return;
    int kl = i & 7;
    size_t r = i >> 3;
    int n = r % 768;
    size_t r2 = r / 768;
    int kh = r2 % 32;
    int l = r2 / 32;
    const float* src = (n < 256) ? Wq : (n < 512) ? Wk : Wv;
    out[i] = (bf16_t)src[(size_t)l * 65536 + (size_t)(kh * 8 + kl) * 256 + (n & 255)];
}

// ---------------- embedding ----------------
__global__ void embed_kernel(const int* __restrict__ x, const float* __restrict__ emb,
                             const float* __restrict__ ch, const float* __restrict__ cls,
                             float* __restrict__ h) {
    int wave = threadIdx.x >> 6, lane = threadIdx.x & 63;
    int row = blockIdx.x * 4 + wave;
    int d0 = lane * 4;
    float4 o;
    int b = row / NSEQ, n = row % NSEQ;
    if (n == 0) {
        o = *(const float4*)(cls + d0);
    } else {
        int idx = n - 1;
        int c = idx / T_, t = idx % T_;
        int tok = x[(b * C_ + c) * T_ + t];
        float4 ev = *(const float4*)(emb + (size_t)tok * 256 + d0);
        float4 cv = *(const float4*)(ch + c * 256 + d0);
        const float kdiv = -0.03597789207803197f;   // -ln(10000)/256
        float f0 = __expf(d0 * kdiv);
        float f2 = __expf((d0 + 2) * kdiv);
        float a0 = t * f0, a2 = t * f2;
        o.x = ev.x + cv.x + sinf(a0);
        o.y = ev.y + cv.y + cosf(a0);
        o.z = ev.z + cv.z + sinf(a2);
        o.w = ev.w + cv.w + cosf(a2);
    }
    *(float4*)(h + (size_t)row * 256 + d0) = o;
}

// ============================================================================
// 128-row A-resident barrier-free GEMM (swapped-operand MFMA, coalesced epi).
// T5 setprio around the per-tile MFMA cluster.
// SRC 0: A = layer_norm(h fp32).  EPI 0: Cb = bf16(acc).  EPI 1: Cf += acc+bias.
// ============================================================================
template <int SRC, int EPI, int NT>
__launch_bounds__(512)
__global__ void gemm_ar(const void* __restrict__ Asrc, const float* __restrict__ lng,
                        const float* __restrict__ lnb, const bf16_t* __restrict__ Wp,
                        const float* __restrict__ bias, float* __restrict__ Cf,
                        bf16_t* __restrict__ Cb, int N) {
    __shared__ bf16_t yn[128 * 256];
    int tid = threadIdx.x;
    int row0 = blockIdx.y * 128;
    int row = tid >> 2, q4 = tid & 3;
    int sx = row & 7;

    if (SRC == 0) {
        const float* rp = (const float*)Asrc + (size_t)(row0 + row) * 256;
        bool ok = (row0 + row) < M_;
        float v[64];
        float sum = 0.f, sq = 0.f;
        #pragma unroll
        for (int j = 0; j < 16; ++j) {
            float4 t = ok ? *(const float4*)(rp + (q4 + j * 4) * 4)
                          : float4{0.f, 0.f, 0.f, 0.f};
            v[j*4+0] = t.x; v[j*4+1] = t.y; v[j*4+2] = t.z; v[j*4+3] = t.w;
            sum += t.x + t.y + t.z + t.w;
            sq  += t.x*t.x + t.y*t.y + t.z*t.z + t.w*t.w;
        }
        sum += __shfl_xor(sum, 1); sum += __shfl_xor(sum, 2);
        sq  += __shfl_xor(sq, 1);  sq  += __shfl_xor(sq, 2);
        float mean = sum * (1.f/256.f);
        float var  = sq * (1.f/256.f) - mean*mean;
        float rs = rsqrtf(var + EPS_);
        #pragma unroll
        for (int j = 0; j < 16; ++j) {
            int ce = q4 + j * 4;
            int colb = ce * 4;
            float4 gv = *(const float4*)(lng + colb);
            float4 bv = *(const float4*)(lnb + colb);
            bf16x4 o4;
            o4[0] = (bf16_t)((v[j*4+0]-mean)*rs*gv.x + bv.x);
            o4[1] = (bf16_t)((v[j*4+1]-mean)*rs*gv.y + bv.y);
            o4[2] = (bf16_t)((v[j*4+2]-mean)*rs*gv.z + bv.z);
            o4[3] = (bf16_t)((v[j*4+3]-mean)*rs*gv.w + bv.w);
            int cg = ce >> 1, hf = ce & 1;
            *(bf16x4*)(&yn[row*256 + ((cg ^ sx) << 3) + hf*4]) = o4;
        }
    } else {
        const bf16_t* rp = (const bf16_t*)Asrc + (size_t)(row0 + row) * 256;
        #pragma unroll
        for (int j = 0; j < 8; ++j) {
            int cg = q4 * 8 + j;
            bf16x8 t = *(const bf16x8*)(rp + cg * 8);
            *(bf16x8*)(&yn[row*256 + ((cg ^ sx) << 3)]) = t;
        }
    }
    __syncthreads();

    int lane = tid & 63, wave = tid >> 6;
    int l15 = lane & 15, ksel = lane >> 4;
    #pragma unroll
    for (int t = 0; t < NT; ++t) {
        int tbase = (blockIdx.x * NT + t) * 128 + wave * 16;
        int col = tbase + l15;
        const bf16_t* bp = Wp + ((size_t)ksel * N + col) * 8;
        f32x4 acc[8] = {};
        __builtin_amdgcn_s_setprio(1);
        #pragma unroll
        for (int kk = 0; kk < 8; ++kk) {
            bf16x8 bf = *(const bf16x8*)(bp + (size_t)kk * 32 * N);
            #pragma unroll
            for (int m = 0; m < 8; ++m) {
                int r = m * 16 + l15;
                bf16x8 af = *(const bf16x8*)(&yn[r*256 + (((kk*4+ksel) ^ (r&7)) << 3)]);
                acc[m] = __builtin_amdgcn_mfma_f32_16x16x32_bf16(bf, af, acc[m], 0, 0, 0);
            }
        }
        __builtin_amdgcn_s_setprio(0);
        int colb = tbase + ksel * 4;
        #pragma unroll
        for (int m = 0; m < 8; ++m) {
            int r = row0 + m * 16 + l15;
            if (r < M_) {
                if (EPI == 0) {
                    bf16x4 o4;
                    #pragma unroll
                    for (int i = 0; i < 4; ++i) o4[i] = (bf16_t)acc[m][i];
                    *(bf16x4*)(Cb + (size_t)r * N + colb) = o4;
                } else {
                    float4 bv = *(const float4*)(bias + colb);
                    float4* hp = (float4*)(Cf + (size_t)r * 256 + colb);
                    float4 hv = *hp;
                    hv.x += acc[m][0] + bv.x; hv.y += acc[m][1] + bv.y;
                    hv.z += acc[m][2] + bv.z; hv.w += acc[m][3] + bv.w;
                    *hp = hv;
                }
            }
        }
    }
}

// ---------------- ctx partial: sum_n exp(k)*v ; colsum ----------------
__global__ void ctx_kernel(const bf16_t* __restrict__ qkv,
                           float* __restrict__ ctx_part, float* __restrict__ colsum_part) {
    int blk = blockIdx.x;                // bh*8 + s
    int bh = blk >> 3, s = blk & 7;
    int b = bh >> 3, hh = bh & 7;
    int n0 = s * 257, n1 = min(n0 + 257, NSEQ);
    int d = threadIdx.x & 31, eg = threadIdx.x >> 5;
    float acc[4] = {0.f, 0.f, 0.f, 0.f};
    float ksum = 0.f;
    __shared__ float ks[64][32];
    __shared__ float vs[64][32];
    const bf16_t* kbase = qkv + (size_t)b * NSEQ * 768 + 256 + hh * 32;
    const bf16_t* vbase = kbase + 256;
    int lr = threadIdx.x >> 2, lc = (threadIdx.x & 3) * 8;
    for (int c0 = n0; c0 < n1; c0 += 64) {
        int rows = min(64, n1 - c0);
        if (lr < rows) {
            bf16x8 kv8 = *(const bf16x8*)(kbase + (size_t)(c0 + lr) * 768 + lc);
            bf16x8 vv8 = *(const bf16x8*)(vbase + (size_t)(c0 + lr) * 768 + lc);
            #pragma unroll
            for (int j = 0; j < 8; ++j) {
                ks[lr][lc + j] = (float)kv8[j];
                vs[lr][lc + j] = (float)vv8[j];
            }
        }
        __syncthreads();
        for (int r = 0; r < rows; ++r) {
            float ek = __expf(ks[r][d]);
            if (eg == 0) ksum += ek;
            const float* vr = &vs[r][eg * 4];
            acc[0] += ek * vr[0]; acc[1] += ek * vr[1];
            acc[2] += ek * vr[2]; acc[3] += ek * vr[3];
        }
        __syncthreads();
    }
    float* cp = ctx_part + ((size_t)blk * 32 + d) * 32 + eg * 4;
    cp[0] = acc[0]; cp[1] = acc[1]; cp[2] = acc[2]; cp[3] = acc[3];
    if (eg == 0) colsum_part[blk * 32 + d] = ksum;
}

// ============================================================================
// CW assembly: CW_b[h*32+d][c] = (sum_s ctxp)/csum  @  Wo_h  -> W' bf16 layout.
// ============================================================================
__global__ void cw_kernel(const float* __restrict__ ctxp, const float* __restrict__ csump,
                          const float* __restrict__ Wo, bf16_t* __restrict__ cwp) {
    int bh = blockIdx.x, b = bh >> 3, hh = bh & 7;
    __shared__ float ctxn[1024];    // [d][e]
    __shared__ float cs[32];
    __shared__ float wos[32][257];  // [e][c], padded
    int t = threadIdx.x;
    for (int i = t; i < 1024; i += 256) {
        float s = 0.f;
        #pragma unroll
        for (int ss = 0; ss < 8; ++ss) s += ctxp[(size_t)(bh * 8 + ss) * 1024 + i];
        ctxn[i] = s;
    }
    if (t < 32) {
        float s = 0.f;
        #pragma unroll
        for (int ss = 0; ss < 8; ++ss) s += csump[(bh * 8 + ss) * 32 + t];
        cs[t] = s;
    }
    for (int i = t; i < 8192; i += 256) {
        int e = i >> 8, c = i & 255;
        wos[e][c] = Wo[(size_t)(hh * 32 + e) * 256 + c];
    }
    __syncthreads();
    float out[32] = {};
    #pragma unroll 4
    for (int e = 0; e < 32; ++e) {
        float w = wos[e][t];
        #pragma unroll
        for (int d = 0; d < 32; ++d) out[d] += ctxn[d * 32 + e] * w;
    }
    #pragma unroll
    for (int d = 0; d < 32; ++d) {
        int kh = hh * 4 + (d >> 3);
        cwp[((size_t)(b * 32 + kh) * 256 + t) * 8 + (d & 7)] = (bf16_t)(out[d] / cs[d]);
    }
}

// ============================================================================
// P@CW gemm: h += softmax32(q)*scale @ CW_b + bo.
// 64-row stripes, grid (1, 33, 16) = 528 blocks (~2/CU, balanced).
// ============================================================================
__launch_bounds__(512)
__global__ void gemm_pv(const bf16_t* __restrict__ qkv, const bf16_t* __restrict__ cwp,
                        const float* __restrict__ bo, float* __restrict__ h) {
    __shared__ bf16_t yn[64 * 256];   // 32 KB
    int tid = threadIdx.x;
    int b = blockIdx.z;
    int row0l = blockIdx.y * 64;
    int row = tid >> 3, t8 = tid & 7;   // 8 threads/row, each owns one 32-elem head group
    int sx = row & 7;
    {
        int rl = row0l + row;
        bool ok = rl < NSEQ;
        const bf16_t* qp = qkv + ((size_t)b * NSEQ + (ok ? rl : 0)) * 768 + t8 * 32;
        float v[32];
        float mx = -1e30f;
        #pragma unroll
        for (int jj = 0; jj < 4; ++jj) {
            bf16x8 t8v = *(const bf16x8*)(qp + jj * 8);
            #pragma unroll
            for (int e = 0; e < 8; ++e) {
                float f = (float)t8v[e];
                v[jj * 8 + e] = f;
                mx = fmaxf(mx, f);
            }
        }
        float s = 0.f;
        #pragma unroll
        for (int e2 = 0; e2 < 32; ++e2) { v[e2] = __expf(v[e2] - mx); s += v[e2]; }
        float p = ok ? (0.17677669529663689f / s) : 0.f;
        #pragma unroll
        for (int j = 0; j < 4; ++j) {
            int c = t8 * 4 + j;
            bf16x8 o8;
            #pragma unroll
            for (int e3 = 0; e3 < 8; ++e3) o8[e3] = (bf16_t)(v[j * 8 + e3] * p);
            *(bf16x8*)(&yn[row * 256 + ((c ^ sx) << 3)]) = o8;
        }
    }
    __syncthreads();

    int lane = tid & 63, wave = tid >> 6;
    int l15 = lane & 15, ksel = lane >> 4;
    int sxr = l15 & 7;
    const bf16_t* CWb = cwp + (size_t)b * 32 * 256 * 8;
    #pragma unroll
    for (int t = 0; t < 2; ++t) {
        int tbase = t * 128 + wave * 16;
        int col = tbase + l15;
        const bf16_t* bp = CWb + ((size_t)ksel * 256 + col) * 8;
        f32x4 acc[4] = {};
        __builtin_amdgcn_s_setprio(1);
        #pragma unroll
        for (int kk = 0; kk < 8; ++kk) {
            bf16x8 bf = *(const bf16x8*)(bp + (size_t)kk * 32 * 256);
            #pragma unroll
            for (int m = 0; m < 4; ++m) {
                int r = m * 16 + l15;
                bf16x8 af = *(const bf16x8*)(&yn[r*256 + (((kk*4+ksel) ^ sxr) << 3)]);
                acc[m] = __builtin_amdgcn_mfma_f32_16x16x32_bf16(bf, af, acc[m], 0, 0, 0);
            }
        }
        __builtin_amdgcn_s_setprio(0);
        int colb = tbase + ksel * 4;
        float4 bv = *(const float4*)(bo + colb);
        #pragma unroll
        for (int m = 0; m < 4; ++m) {
            int rl = row0l + m * 16 + l15;
            if (rl < NSEQ) {
                float4* hp = (float4*)(h + ((size_t)b * NSEQ + rl) * 256 + colb);
                float4 hv = *hp;
                hv.x += acc[m][0] + bv.x; hv.y += acc[m][1] + bv.y;
                hv.z += acc[m][2] + bv.z; hv.w += acc[m][3] + bv.w;
                *hp = hv;
            }
        }
    }
}

// ============================================================================
// Fused LN2 + FF1 + GELU + FF2 + residual.  64-row stripe, 8 waves, 48KB LDS.
// T5 setprio around MFMA clusters; T14 early W2 loads (issued at chunk top,
// consumed after 2 barriers -> L2 latency hidden under FF1+gelu).
// ============================================================================
__launch_bounds__(512)
__global__ void fused_ff(const float* __restrict__ hsrc, const float* __restrict__ lng,
                         const float* __restrict__ lnb, const bf16_t* __restrict__ W1p,
                         const float* __restrict__ b1v, const bf16_t* __restrict__ W2p,
                         const float* __restrict__ b2v, float* __restrict__ hio) {
    __shared__ bf16_t yn[64 * 256];   // 32 KB
    __shared__ bf16_t ps[64 * 128];   // 16 KB
    int tid = threadIdx.x;
    int row0 = blockIdx.x * 64;
    int row = tid >> 3, t8 = tid & 7;
    int sx = row & 7;
    {
        const float* rp = hsrc + (size_t)(row0 + row) * 256 + t8 * 32;
        bool ok = (row0 + row) < M_;
        float sum = 0.f, sq = 0.f;
        #pragma unroll
        for (int j = 0; j < 8; ++j) {
            float4 t = ok ? *(const float4*)(rp + j * 4) : float4{0.f, 0.f, 0.f, 0.f};
            sum += t.x + t.y + t.z + t.w;
            sq  += t.x * t.x + t.y * t.y + t.z * t.z + t.w * t.w;
        }
        sum += __shfl_xor(sum, 1); sum += __shfl_xor(sum, 2); sum += __shfl_xor(sum, 4);
        sq  += __shfl_xor(sq, 1);  sq  += __shfl_xor(sq, 2);  sq  += __shfl_xor(sq, 4);
        float mean = sum * (1.f / 256.f);
        float rs = rsqrtf(sq * (1.f / 256.f) - mean * mean + EPS_);
        #pragma unroll
        for (int j = 0; j < 4; ++j) {
            int c = t8 * 4 + j;
            int colb = c * 8;
            float4 a = ok ? *(const float4*)(rp + j * 8)     : float4{0.f, 0.f, 0.f, 0.f};
            float4 b = ok ? *(const float4*)(rp + j * 8 + 4) : float4{0.f, 0.f, 0.f, 0.f};
            float4 g0 = *(const float4*)(lng + colb);
            float4 g1 = *(const float4*)(lng + colb + 4);
            float4 h0 = *(const float4*)(lnb + colb);
            float4 h1 = *(const float4*)(lnb + colb + 4);
            bf16x8 o8;
            o8[0] = (bf16_t)((a.x - mean) * rs * g0.x + h0.x);
            o8[1] = (bf16_t)((a.y - mean) * rs * g0.y + h0.y);
            o8[2] = (bf16_t)((a.z - mean) * rs * g0.z + h0.z);
            o8[3] = (bf16_t)((a.w - mean) * rs * g0.w + h0.w);
            o8[4] = (bf16_t)((b.x - mean) * rs * g1.x + h1.x);
            o8[5] = (bf16_t)((b.y - mean) * rs * g1.y + h1.y);
            o8[6] = (bf16_t)((b.z - mean) * rs * g1.z + h1.z);
            o8[7] = (bf16_t)((b.w - mean) * rs * g1.w + h1.w);
            *(bf16x8*)(&yn[row * 256 + ((c ^ sx) << 3)]) = o8;
        }
    }
    __syncthreads();

    int lane = tid & 63, wave = tid >> 6;
    int l15 = lane & 15, ksel = lane >> 4;
    int sxr = l15 & 7;
    f32x4 oacc[4][2] = {};

    for (int kc = 0; kc < 8; ++kc) {
        // ---- T14: issue W2 loads for this chunk EARLY ----
        bf16x8 w2a0, w2a1, w2a2, w2a3, w2b0, w2b1, w2b2, w2b3;
        {
            const bf16_t* b2base = W2p + (size_t)(kc * 16 + ksel) * 256 * 8;
            const bf16_t* pa = b2base + (size_t)(wave * 32 + l15) * 8;
            const bf16_t* pb = b2base + (size_t)(wave * 32 + 16 + l15) * 8;
            const size_t st = (size_t)4 * 256 * 8;   // kk step = 4 kh rows
            w2a0 = *(const bf16x8*)(pa + 0 * st); w2b0 = *(const bf16x8*)(pb + 0 * st);
            w2a1 = *(const bf16x8*)(pa + 1 * st); w2b1 = *(const bf16x8*)(pb + 1 * st);
            w2a2 = *(const bf16x8*)(pa + 2 * st); w2b2 = *(const bf16x8*)(pb + 2 * st);
            w2a3 = *(const bf16x8*)(pa + 3 * st); w2b3 = *(const bf16x8*)(pb + 3 * st);
        }
        // ---- FF1: pacc = yn @ W1[:, chunk] ----
        int fcol = kc * 128 + wave * 16 + l15;
        const bf16_t* bp = W1p + ((size_t)ksel * 1024 + fcol) * 8;
        f32x4 pacc[4] = {};
        __builtin_amdgcn_s_setprio(1);
        #pragma unroll
        for (int kk = 0; kk < 8; ++kk) {
            bf16x8 bf = *(const bf16x8*)(bp + (size_t)kk * 32 * 1024);
            #pragma unroll
            for (int m = 0; m < 4; ++m) {
                int r = m * 16 + l15;
                bf16x8 af = *(const bf16x8*)(&yn[r * 256 + (((kk * 4 + ksel) ^ sxr) << 3)]);
                pacc[m] = __builtin_amdgcn_mfma_f32_16x16x32_bf16(bf, af, pacc[m], 0, 0, 0);
            }
        }
        __builtin_amdgcn_s_setprio(0);
        float4 b1a = *(const float4*)(b1v + kc * 128 + wave * 16 + ksel * 4);
        __syncthreads();   // previous chunk's FF2 reads of ps are done
        // ---- gelu -> ps ----
        int pcl = wave * 16 + ksel * 4;
        int pc = pcl >> 3, pofs = pcl & 7;
        #pragma unroll
        for (int m = 0; m < 4; ++m) {
            bf16x4 o4;
            o4[0] = (bf16_t)gelu_f(pacc[m][0] + b1a.x);
            o4[1] = (bf16_t)gelu_f(pacc[m][1] + b1a.y);
            o4[2] = (bf16_t)gelu_f(pacc[m][2] + b1a.z);
            o4[3] = (bf16_t)gelu_f(pacc[m][3] + b1a.w);
            *(bf16x4*)(&ps[(m * 16 + l15) * 128 + ((pc ^ sxr) << 3) + pofs]) = o4;
        }
        __syncthreads();
        // ---- FF2 partial: oacc += ps @ W2[chunk, :]  (weights preloaded) ----
        __builtin_amdgcn_s_setprio(1);
        #pragma unroll
        for (int kk = 0; kk < 4; ++kk) {
            bf16x8 bf0 = (kk == 0) ? w2a0 : (kk == 1) ? w2a1 : (kk == 2) ? w2a2 : w2a3;
            bf16x8 bf1 = (kk == 0) ? w2b0 : (kk == 1) ? w2b1 : (kk == 2) ? w2b2 : w2b3;
            #pragma unroll
            for (int m = 0; m < 4; ++m) {
                int r = m * 16 + l15;
                bf16x8 af = *(const bf16x8*)(&ps[r * 128 + (((kk * 4 + ksel) ^ sxr) << 3)]);
                oacc[m][0] = __builtin_amdgcn_mfma_f32_16x16x32_bf16(bf0, af, oacc[m][0], 0, 0, 0);
                oacc[m][1] = __builtin_amdgcn_mfma_f32_16x16x32_bf16(bf1, af, oacc[m][1], 0, 0, 0);
            }
        }
        __builtin_amdgcn_s_setprio(0);
    }

    #pragma unroll
    for (int nf = 0; nf < 2; ++nf) {
        int colb = wave * 32 + nf * 16 + ksel * 4;
        float4 bv = *(const float4*)(b2v + colb);
        #pragma unroll
        for (int m = 0; m < 4; ++m) {
            int r = row0 + m * 16 + l15;
            if (r < M_) {
                float4* hp = (float4*)(hio + (size_t)r * 256 + colb);
                float4 hv = *hp;
                hv.x += oacc[m][nf][0] + bv.x; hv.y += oacc[m][nf][1] + bv.y;
                hv.z += oacc[m][nf][2] + bv.z; hv.w += oacc[m][nf][3] + bv.w;
                *hp = hv;
            }
        }
    }
}

// ---------------- classifier head: one wave per (b, cls) ----------------
__global__ void head_kernel(const float* __restrict__ h, const float* __restrict__ Wh,
                            const float* __restrict__ bh, float* __restrict__ out) {
    int idx = blockIdx.x;                 // 0..79 = b*5 + c
    int b = idx / 5, c = idx % 5;
    int lane = threadIdx.x;
    const float* xp = h + (size_t)b * NSEQ * 256;
    float s = 0.f;
    #pragma unroll
    for (int d0 = 0; d0 < 256; d0 += 64) s += xp[d0 + lane] * Wh[(d0 + lane) * 5 + c];
    s = wave_sum(s);
    if (lane == 0) out[idx] = s + bh[c];
}

extern "C" void kernel_launch(void* const* d_in, const int* in_sizes, int n_in,
                              void* d_out, int out_size, void* d_ws, size_t ws_size,
                              hipStream_t stream) {
    const int*   x    = (const int*)d_in[0];
    const float* emb  = (const float*)d_in[1];
    const float* ch   = (const float*)d_in[2];
    const float* cls  = (const float*)d_in[3];
    const float* Wq   = (const float*)d_in[4];
    const float* Wk   = (const float*)d_in[5];
    const float* Wv   = (const float*)d_in[6];
    const float* Wo   = (const float*)d_in[7];
    const float* bo   = (const float*)d_in[8];
    const float* g1   = (const float*)d_in[9];
    const float* b1   = (const float*)d_in[10];
    const float* W1   = (const float*)d_in[11];
    const float* bf1  = (const float*)d_in[12];
    const float* W2   = (const float*)d_in[13];
    const float* bf2  = (const float*)d_in[14];
    const float* g2   = (const float*)d_in[15];
    const float* b2   = (const float*)d_in[16];
    const float* Wh   = (const float*)d_in[17];
    const float* bh   = (const float*)d_in[18];

    char* ws = (char*)d_ws;
    size_t off = 0;
    float*  h      = (float*)(ws + off);  off += (size_t)M_ * 256 * 4;            // 33,570,816
    bf16_t* qkv    = (bf16_t*)(ws + off); off += (size_t)MPAD * 768 * 2;          // 50,528,256
    float*  ctxp   = (float*)(ws + off);  off += (size_t)16 * 8 * 8 * 1024 * 4;   // 4,194,304
    float*  csump  = (float*)(ws + off);  off += (size_t)16 * 8 * 8 * 32 * 4;     // 131,072
    bf16_t* cwp    = (bf16_t*)(ws + off); off += (size_t)16 * 32 * 256 * 8 * 2;   // 2,097,152
    bf16_t* wqkv_p = (bf16_t*)(ws + off); off += (size_t)L_ * 768 * 256 * 2;      // 4,718,592
    bf16_t* w1_p   = (bf16_t*)(ws + off); off += (size_t)L_ * 1024 * 256 * 2;     // 6,291,456
    bf16_t* w2_p   = (bf16_t*)(ws + off); off += (size_t)L_ * 256 * 1024 * 2;     // 6,291,456
    (void)ws_size; (void)in_sizes; (void)n_in; (void)out_size;

    conv_wq3<<<9216, 256, 0, stream>>>(Wq, Wk, Wv, wqkv_p);
    conv_w<<<12288, 256, 0, stream>>>(W1, w1_p, 256, 1024);
    conv_w<<<12288, 256, 0, stream>>>(W2, w2_p, 1024, 256);

    embed_kernel<<<M_ / 4, 256, 0, stream>>>(x, emb, ch, cls, h);

    for (int l = 0; l < L_; ++l) {
        // LN1 + QKV -> qkv bf16 [M][768]
        gemm_ar<0, 0, 3><<<dim3(2, 257), 512, 0, stream>>>(
            h, g1 + l * 256, b1 + l * 256, wqkv_p + (size_t)l * 768 * 256,
            nullptr, nullptr, qkv, 768);
        ctx_kernel<<<1024, 256, 0, stream>>>(qkv, ctxp, csump);
        // CW_b = normalize(ctx) @ Wo_h  -> W' bf16
        cw_kernel<<<128, 256, 0, stream>>>(ctxp, csump, Wo + (size_t)l * 65536, cwp);
        // h += softmax(q)*scale @ CW_b + bo
        gemm_pv<<<dim3(1, 33, 16), 512, 0, stream>>>(qkv, cwp, bo + l * 256, h);
        // LN2 + FF1 + GELU + FF2 + residual (fused)
        fused_ff<<<513, 512, 0, stream>>>(
            h, g2 + l * 256, b2 + l * 256, w1_p + (size_t)l * 1024 * 256,
            bf1 + l * 1024, w2_p + (size_t)l * 256 * 1024, bf2 + l * 256, h);
    }

    head_kernel<<<80, 64, 0, stream>>>(h, Wh, bh, (float*)d_out);
}